// Round 2
// baseline (1481.281 us; speedup 1.0000x reference)
//
#include <hip/hip_runtime.h>
#include <hip/hip_bf16.h>

typedef unsigned short u16;
typedef __attribute__((ext_vector_type(8))) short short8;
typedef __attribute__((ext_vector_type(8))) __bf16 bfrag;   // 8 bf16 = 4 VGPRs (MFMA A/B operand)
typedef __attribute__((ext_vector_type(4))) float cfrag;    // MFMA C/D operand

#define T_TOK   8192      // B*S
#define D_MODEL 1024
#define E_EXP   8
#define DFF     4096      // per-GLU-half width (8*D/2)
#define NPAIR   16384     // T_TOK * TOPK
#define MAXTILE 136       // sum_e ceil(n_e/128) <= 135

__device__ __forceinline__ u16 f2bf(float f) {
    __hip_bfloat16 h = __float2bfloat16(f);
    return __builtin_bit_cast(u16, h);
}
// async global->LDS, 16B per lane; LDS dest = wave-uniform base + lane*16
__device__ __forceinline__ void gld_lds16(const u16* g, u16* l) {
    __builtin_amdgcn_global_load_lds(
        (const __attribute__((address_space(1))) void*)g,
        (__attribute__((address_space(3))) void*)l, 16, 0, 0);
}
__device__ __forceinline__ cfrag mfma16(bfrag a, bfrag b, cfrag c) {
    return __builtin_amdgcn_mfma_f32_16x16x32_bf16(a, b, c, 0, 0, 0);
}

// ---------------- routing ----------------
__global__ __launch_bounds__(256) void k_zero(int* cnt) {
    if (threadIdx.x < 64) cnt[threadIdx.x] = 0;
}

// one wave per token: logits = x @ router_w + b (all fp32), top-2, softmax, histogram
__global__ __launch_bounds__(256) void k_route(
    const float* __restrict__ x, const float* __restrict__ rw, const float* __restrict__ rb,
    int* __restrict__ tope, float* __restrict__ wpair, int* __restrict__ cnt)
{
    __shared__ float rws[D_MODEL * E_EXP];   // 32 KB
    int tid = threadIdx.x;
    for (int i = tid; i < D_MODEL * E_EXP; i += 256) rws[i] = rw[i];
    __syncthreads();
    int wid = tid >> 6, lane = tid & 63;
    int t = blockIdx.x * 4 + wid;
    const float4* xp = (const float4*)(x + (size_t)t * D_MODEL + lane * 16);
    float xv[16];
#pragma unroll
    for (int j = 0; j < 4; j++) {
        float4 v = xp[j];
        xv[4 * j] = v.x; xv[4 * j + 1] = v.y; xv[4 * j + 2] = v.z; xv[4 * j + 3] = v.w;
    }
    float acc[E_EXP];
#pragma unroll
    for (int e = 0; e < E_EXP; e++) acc[e] = 0.f;
#pragma unroll
    for (int i = 0; i < 16; i++) {
        float xf = xv[i];
        const float* r = &rws[(lane * 16 + i) * E_EXP];
#pragma unroll
        for (int e = 0; e < E_EXP; e++) acc[e] += xf * r[e];
    }
#pragma unroll
    for (int e = 0; e < E_EXP; e++) {
        float v = acc[e];
#pragma unroll
        for (int s = 32; s > 0; s >>= 1) v += __shfl_xor(v, s, 64);
        acc[e] = v;
    }
    if (lane == 0) {
        float lg[E_EXP];
#pragma unroll
        for (int e = 0; e < E_EXP; e++) lg[e] = acc[e] + rb[e];
        int e0 = 0;
        for (int e = 1; e < E_EXP; e++) if (lg[e] > lg[e0]) e0 = e;   // ties -> lowest idx
        int e1 = -1;
        for (int e = 0; e < E_EXP; e++) {
            if (e == e0) continue;
            if (e1 < 0 || lg[e] > lg[e1]) e1 = e;
        }
        float p0 = 1.f / (1.f + expf(lg[e1] - lg[e0]));   // softmax over top-2
        tope[2 * t] = e0;  tope[2 * t + 1] = e1;
        wpair[2 * t] = p0; wpair[2 * t + 1] = 1.f - p0;
        atomicAdd(&cnt[e0], 1); atomicAdd(&cnt[e1], 1);
    }
}

// exclusive scan of counts + row-tile table (tiles of 128 rows per expert segment)
__global__ void k_scan(const int* __restrict__ cnt, int* __restrict__ cursor,
                       int4* __restrict__ table, int* __restrict__ ntiles)
{
    if (threadIdx.x == 0 && blockIdx.x == 0) {
        int off[E_EXP + 1]; off[0] = 0;
        for (int e = 0; e < E_EXP; e++) off[e + 1] = off[e] + cnt[e];
        for (int e = 0; e < E_EXP; e++) cursor[e] = off[e];
        int nt = 0;
        for (int e = 0; e < E_EXP; e++)
            for (int r = off[e]; r < off[e + 1]; r += 128)
                table[nt++] = make_int4(e, r, off[e + 1], 0);
        *ntiles = nt;
    }
}

// counting-sort scatter: perm[p]=pair-id, inv[pair-id]=p, wperm[p]=combine weight
__global__ __launch_bounds__(256) void k_permute(
    const int* __restrict__ tope, const float* __restrict__ wpair,
    int* __restrict__ cursor, int* __restrict__ perm,
    int* __restrict__ inv, float* __restrict__ wperm)
{
    int i = blockIdx.x * 256 + threadIdx.x;
    int e = tope[i];
    int p = atomicAdd(&cursor[e], 1);
    perm[p] = i; inv[i] = p; wperm[p] = wpair[i];
}

// ---------------- x fp32 -> bf16 ----------------
__global__ __launch_bounds__(256) void k_cvt_x(
    const float* __restrict__ x, u16* __restrict__ xb)
{
    int i = blockIdx.x * 256 + threadIdx.x;   // one octet per thread
    const float4* xp = (const float4*)(x + (size_t)i * 8);
    float4 v0 = xp[0], v1 = xp[1];
    short8 o;
    o[0] = (short)f2bf(v0.x); o[1] = (short)f2bf(v0.y);
    o[2] = (short)f2bf(v0.z); o[3] = (short)f2bf(v0.w);
    o[4] = (short)f2bf(v1.x); o[5] = (short)f2bf(v1.y);
    o[6] = (short)f2bf(v1.z); o[7] = (short)f2bf(v1.w);
    *(short8*)(xb + (size_t)i * 8) = o;
}

// ------- weight transpose + cast:  W fp32 [e][K][N] -> WT bf16 [e][N][K] -------
__global__ __launch_bounds__(256) void k_transpose(
    const float* __restrict__ W, u16* __restrict__ WT, int K, int N)
{
    __shared__ u16 tile[64][65];
    int e = blockIdx.z;
    const float* Wp = W + (size_t)e * K * N;
    u16* Tp = WT + (size_t)e * K * N;
    int n0 = blockIdx.x * 64, k0 = blockIdx.y * 64;
    int t = threadIdx.x;
    int rr = t >> 4, cc = (t & 15) * 4;      // 16 threads/row, float4 each
#pragma unroll
    for (int it = 0; it < 4; ++it) {
        int kr = rr + it * 16;
        float4 v = *(const float4*)(Wp + (size_t)(k0 + kr) * N + n0 + cc);
        tile[kr][cc + 0] = f2bf(v.x); tile[kr][cc + 1] = f2bf(v.y);
        tile[kr][cc + 2] = f2bf(v.z); tile[kr][cc + 3] = f2bf(v.w);
    }
    __syncthreads();
    int nr2 = t >> 3, cc2 = (t & 7) * 8;     // 8 threads/row, short8 each
#pragma unroll
    for (int it = 0; it < 2; ++it) {
        int nr = nr2 + it * 32;
        short8 v;
#pragma unroll
        for (int i = 0; i < 8; i++) v[i] = (short)tile[cc2 + i][nr];
        *(short8*)(Tp + (size_t)(n0 + nr) * K + k0 + cc2) = v;
    }
}

// ---------------- up-GEMM + GLU (exact gelu) ----------------
// act[p][j] = (xW_a + b_a) * gelu(xW_g + b_g),  rows p grouped by expert
__global__ __launch_bounds__(256, 2) void k_up_glu(
    const u16* __restrict__ xb, const u16* __restrict__ upT, const float* __restrict__ upb,
    const int* __restrict__ perm, const int4* __restrict__ table,
    const int* __restrict__ ntiles, u16* __restrict__ act)
{
    if ((int)blockIdx.x >= *ntiles) return;
    int4 ti = table[blockIdx.x];
    int e = ti.x, row0 = ti.y, rend = ti.z;
    int n0 = blockIdx.y * 64;
    __shared__ __align__(16) u16 As[128 * 32];
    __shared__ __align__(16) u16 Bs[2][64 * 32];
    int tid = threadIdx.x, lane = tid & 63, wid = tid >> 6;
    int ar = tid >> 2, kc = (tid & 3) * 8;
    int t1 = perm[min(row0 + ar,       rend - 1)] >> 1;
    int t2 = perm[min(row0 + ar + 64,  rend - 1)] >> 1;
    const u16* ga1 = xb + (size_t)t1 * D_MODEL + kc;
    const u16* ga2 = xb + (size_t)t2 * D_MODEL + kc;
    const u16* gb0 = upT + ((size_t)e * 2 * DFF + n0 + ar) * D_MODEL + kc;
    const u16* gb1 = gb0 + (size_t)DFF * D_MODEL;
    u16* lA0 = As + wid * 16 * 32;
    u16* lA1 = As + (64 + wid * 16) * 32;
    u16* lB0 = Bs[0] + wid * 16 * 32;
    u16* lB1 = Bs[1] + wid * 16 * 32;
    cfrag acc[2][4][2];
#pragma unroll
    for (int h = 0; h < 2; h++)
#pragma unroll
        for (int m = 0; m < 4; m++)
#pragma unroll
            for (int n = 0; n < 2; n++) acc[h][m][n] = (cfrag)0.f;
    int wrow = (wid >> 1) * 64, wcol = (wid & 1) * 32;
    int qoff = (lane >> 4) * 8;
    for (int k0 = 0; k0 < D_MODEL; k0 += 32) {
        __syncthreads();
        gld_lds16(ga1, lA0); gld_lds16(ga2, lA1);
        gld_lds16(gb0, lB0); gld_lds16(gb1, lB1);
        ga1 += 32; ga2 += 32; gb0 += 32; gb1 += 32;
        __syncthreads();
        bfrag af[4];
#pragma unroll
        for (int m = 0; m < 4; m++)
            af[m] = __builtin_bit_cast(bfrag, *(const short8*)&As[(wrow + m * 16 + (lane & 15)) * 32 + qoff]);
#pragma unroll
        for (int h = 0; h < 2; h++) {
#pragma unroll
            for (int n = 0; n < 2; n++) {
                bfrag bv = __builtin_bit_cast(bfrag, *(const short8*)&Bs[h][(wcol + n * 16 + (lane & 15)) * 32 + qoff]);
#pragma unroll
                for (int m = 0; m < 4; m++) acc[h][m][n] = mfma16(af[m], bv, acc[h][m][n]);
            }
        }
    }
    const float* ub = upb + (size_t)e * 2 * DFF;
#pragma unroll
    for (int m = 0; m < 4; m++) {
        int rbase = row0 + wrow + m * 16 + ((lane >> 4) << 2);
#pragma unroll
        for (int n = 0; n < 2; n++) {
            int j = n0 + wcol + n * 16 + (lane & 15);
            float ba = ub[j];
            float bg = ub[j + DFF];
#pragma unroll
            for (int r = 0; r < 4; r++) {
                int p = rbase + r;
                if (p < rend) {
                    float a = acc[0][m][n][r] + ba;
                    float g = acc[1][m][n][r] + bg;
                    float gl = 0.5f * g * (1.f + erff(g * 0.70710678118f));
                    act[(size_t)p * DFF + j] = f2bf(a * gl);
                }
            }
        }
    }
}

// ---------------- down-GEMM, epilogue: (acc + bias) * combine_weight ----------------
__global__ __launch_bounds__(256, 2) void k_down(
    const u16* __restrict__ act, const u16* __restrict__ dT, const float* __restrict__ db,
    const float* __restrict__ wperm, const int4* __restrict__ table,
    const int* __restrict__ ntiles, float* __restrict__ ys)
{
    if ((int)blockIdx.x >= *ntiles) return;
    int4 ti = table[blockIdx.x];
    int e = ti.x, row0 = ti.y, rend = ti.z;
    int n0 = blockIdx.y * 128;
    __shared__ __align__(16) u16 As[128 * 32];
    __shared__ __align__(16) u16 Bs[128 * 32];
    int tid = threadIdx.x, lane = tid & 63, wid = tid >> 6;
    int ar = tid >> 2, kc = (tid & 3) * 8;
    int p1 = min(row0 + ar,      rend - 1);
    int p2 = min(row0 + ar + 64, rend - 1);
    const u16* ga1 = act + (size_t)p1 * DFF + kc;
    const u16* ga2 = act + (size_t)p2 * DFF + kc;
    const u16* gb1 = dT + ((size_t)e * D_MODEL + n0 + ar) * DFF + kc;
    const u16* gb2 = gb1 + (size_t)64 * DFF;
    u16* lA0 = As + wid * 16 * 32;
    u16* lA1 = As + (64 + wid * 16) * 32;
    u16* lB0 = Bs + wid * 16 * 32;
    u16* lB1 = Bs + (64 + wid * 16) * 32;
    cfrag acc[4][4];
#pragma unroll
    for (int m = 0; m < 4; m++)
#pragma unroll
        for (int n = 0; n < 4; n++) acc[m][n] = (cfrag)0.f;
    int wrow = (wid >> 1) * 64, wcol = (wid & 1) * 64;
    int qoff = (lane >> 4) * 8;
    for (int k0 = 0; k0 < DFF; k0 += 32) {
        __syncthreads();
        gld_lds16(ga1, lA0); gld_lds16(ga2, lA1);
        gld_lds16(gb1, lB0); gld_lds16(gb2, lB1);
        ga1 += 32; ga2 += 32; gb1 += 32; gb2 += 32;
        __syncthreads();
        bfrag af[4], bv[4];
#pragma unroll
        for (int m = 0; m < 4; m++)
            af[m] = __builtin_bit_cast(bfrag, *(const short8*)&As[(wrow + m * 16 + (lane & 15)) * 32 + qoff]);
#pragma unroll
        for (int n = 0; n < 4; n++)
            bv[n] = __builtin_bit_cast(bfrag, *(const short8*)&Bs[(wcol + n * 16 + (lane & 15)) * 32 + qoff]);
#pragma unroll
        for (int m = 0; m < 4; m++)
#pragma unroll
            for (int n = 0; n < 4; n++) acc[m][n] = mfma16(af[m], bv[n], acc[m][n]);
    }
    const float* dbp = db + (size_t)e * D_MODEL;
#pragma unroll
    for (int m = 0; m < 4; m++) {
        int rbase = row0 + wrow + m * 16 + ((lane >> 4) << 2);
#pragma unroll
        for (int n = 0; n < 4; n++) {
            int col = n0 + wcol + n * 16 + (lane & 15);
            float bias = dbp[col];
#pragma unroll
            for (int r = 0; r < 4; r++) {
                int p = rbase + r;
                if (p < rend)
                    ys[(size_t)p * D_MODEL + col] = (acc[m][n][r] + bias) * wperm[p];
            }
        }
    }
}

// ---------------- combine: out[t] = ys[inv[2t]] + ys[inv[2t+1]]  (fp32) ----------------
__global__ __launch_bounds__(256) void k_combine(
    const float* __restrict__ ys, const int* __restrict__ inv, float* __restrict__ out)
{
    int i = blockIdx.x * 256 + threadIdx.x;   // one float4 per thread over T*D/4
    int t = i >> 8;
    int c = (i & 255) << 2;
    int r0 = inv[2 * t], r1 = inv[2 * t + 1];
    float4 a = *(const float4*)&ys[(size_t)r0 * D_MODEL + c];
    float4 b = *(const float4*)&ys[(size_t)r1 * D_MODEL + c];
    float4 o = make_float4(a.x + b.x, a.y + b.y, a.z + b.z, a.w + b.w);
    *(float4*)&out[(size_t)t * D_MODEL + c] = o;
}

extern "C" void kernel_launch(void* const* d_in, const int* in_sizes, int n_in,
                              void* d_out, int out_size, void* d_ws, size_t ws_size,
                              hipStream_t stream)
{
    const float* x   = (const float*)d_in[0];   // [T,1024] fp32
    const float* rw  = (const float*)d_in[1];   // [1024,8]
    const float* rb  = (const float*)d_in[2];   // [8]
    const float* upw = (const float*)d_in[3];   // [8,1024,8192]
    const float* upb = (const float*)d_in[4];   // [8,8192]
    const float* dw  = (const float*)d_in[5];   // [8,4096,1024]
    const float* db  = (const float*)d_in[6];   // [8,1024]
    float* out = (float*)d_out;

    char* ws = (char*)d_ws;
    size_t o = 0;
    auto alloc = [&](size_t bytes) -> char* {
        char* p = ws + o; o += (bytes + 255) & ~(size_t)255; return p;
    };
    u16*  upT = (u16*)alloc((size_t)E_EXP * 2 * DFF * D_MODEL * 2);   // 128 MiB bf16 [E][8192][1024]
    u16*  dT  = (u16*)alloc((size_t)E_EXP * D_MODEL * DFF * 2);       //  64 MiB bf16 [E][1024][4096]
    u16*  xb  = (u16*)alloc((size_t)T_TOK * D_MODEL * 2);             //  16 MiB bf16
    u16*  act = (u16*)alloc((size_t)NPAIR * DFF * 2);                 // 128 MiB bf16
    // ys (fp32, 64 MiB) aliases upT: upT is dead once k_up_glu completes,
    // and k_down (the writer of ys) runs strictly after it on the stream.
    float* ysb = (float*)upT;
    int*   tope  = (int*)alloc(NPAIR * 4);
    float* wpair = (float*)alloc(NPAIR * 4);
    int*   perm  = (int*)alloc(NPAIR * 4);
    int*   inv   = (int*)alloc(NPAIR * 4);
    float* wperm = (float*)alloc(NPAIR * 4);
    int*   cnt    = (int*)alloc(64 * 4);
    int*   cursor = (int*)alloc(64 * 4);
    int4*  table  = (int4*)alloc(160 * 16);
    int*   ntiles = (int*)alloc(256);
    (void)in_sizes; (void)n_in; (void)out_size; (void)ws_size;

    k_zero<<<1, 256, 0, stream>>>(cnt);
    k_route<<<T_TOK / 4, 256, 0, stream>>>(x, rw, rb, tope, wpair, cnt);
    k_scan<<<1, 64, 0, stream>>>(cnt, cursor, table, ntiles);
    k_permute<<<NPAIR / 256, 256, 0, stream>>>(tope, wpair, cursor, perm, inv, wperm);
    k_cvt_x<<<(T_TOK * D_MODEL / 8) / 256, 256, 0, stream>>>(x, xb);
    k_transpose<<<dim3(8192 / 64, 1024 / 64, E_EXP), 256, 0, stream>>>(upw, upT, 1024, 8192);
    k_transpose<<<dim3(1024 / 64, 4096 / 64, E_EXP), 256, 0, stream>>>(dw, dT, 4096, 1024);
    k_up_glu<<<dim3(MAXTILE, DFF / 64), 256, 0, stream>>>(xb, upT, upb, perm, table, ntiles, act);
    k_down<<<dim3(MAXTILE, D_MODEL / 128), 256, 0, stream>>>(act, dT, db, wperm, table, ntiles, ysb);
    k_combine<<<(T_TOK * D_MODEL / 4) / 256, 256, 0, stream>>>(ysb, inv, out);
}